// Round 8
// baseline (362.582 us; speedup 1.0000x reference)
//
#include <hip/hip_runtime.h>
#include <hip/hip_bf16.h>
#include <cstdint>

typedef __attribute__((ext_vector_type(8))) __bf16 bf16x8;
typedef __attribute__((ext_vector_type(4))) __bf16 bf16x4;
typedef __attribute__((ext_vector_type(4))) float f32x4;
typedef __attribute__((ext_vector_type(4))) unsigned int uint32x4;

#define MFMA16(a, b, c) __builtin_amdgcn_mfma_f32_16x16x32_bf16(a, b, c, 0, 0, 0)

static constexpr float SCQ = 0.18033688f;  // (1/sqrt(64)) * log2(e)

__device__ __forceinline__ void gload16(const void* g, void* l) {
  __builtin_amdgcn_global_load_lds(
      (const __attribute__((address_space(1))) void*)g,
      (__attribute__((address_space(3))) void*)l, 16, 0, 0);
}

// pack two f32 -> one dword of 2 bf16 (RNE), single HW instruction
__device__ __forceinline__ unsigned int cvtpk(float lo, float hi) {
  unsigned int r;
  asm("v_cvt_pk_bf16_f32 %0, %1, %2" : "=v"(r) : "v"(lo), "v"(hi));
  return r;
}

// ---------------------------------------------------------------------------
// conv_x: f32 [8192][1024] -> bf16 same layout
// ---------------------------------------------------------------------------
__global__ __launch_bounds__(256) void conv_x(const float* __restrict__ in,
                                              __bf16* __restrict__ out) {
  const size_t i = ((size_t)blockIdx.x * 256 + threadIdx.x) * 8;
  const float4 v0 = *(const float4*)(in + i);
  const float4 v1 = *(const float4*)(in + i + 4);
  bf16x8 o = {(__bf16)v0.x, (__bf16)v0.y, (__bf16)v0.z, (__bf16)v0.w,
              (__bf16)v1.x, (__bf16)v1.y, (__bf16)v1.z, (__bf16)v1.w};
  *(bf16x8*)(out + i) = o;
}

// ---------------------------------------------------------------------------
// conv_wt: W f32 [K][N] -> Wt bf16 [N][K]  (transpose via LDS tile)
// ---------------------------------------------------------------------------
__global__ __launch_bounds__(256) void conv_wt(const float* __restrict__ W,
                                               __bf16* __restrict__ Wt,
                                               int K, int N) {
  __shared__ float tile[64][65];
  const int nb = blockIdx.x * 64, kb = blockIdx.y * 64;
  const int t = threadIdx.x, tr = t >> 4, tc = t & 15;
  #pragma unroll
  for (int p = 0; p < 4; ++p) {
    const float4 v =
        *(const float4*)(W + (size_t)(kb + p * 16 + tr) * N + nb + tc * 4);
    tile[p * 16 + tr][tc * 4 + 0] = v.x;
    tile[p * 16 + tr][tc * 4 + 1] = v.y;
    tile[p * 16 + tr][tc * 4 + 2] = v.z;
    tile[p * 16 + tr][tc * 4 + 3] = v.w;
  }
  __syncthreads();
  #pragma unroll
  for (int p = 0; p < 4; ++p) {
    const int n = p * 16 + tr, kk = tc * 4;
    bf16x4 o = {(__bf16)tile[kk + 0][n], (__bf16)tile[kk + 1][n],
                (__bf16)tile[kk + 2][n], (__bf16)tile[kk + 3][n]};
    *(bf16x4*)(Wt + (size_t)(nb + n) * K + kb + kk) = o;
  }
}

// ---------------------------------------------------------------------------
// GEMM core (m97 structure): 128x128 tile, BK=32, global_load_lds w=16,
// linear LDS, flat grid with bijective XCD swizzle (T1).
// V stored sigma-permuted: key s (w=s&31=4a+b) -> col (s&~31)+8*(a&3)+4*(a>>2)+b
// so attention's PV B-fragments are MFMA-lane-ordered.
// ---------------------------------------------------------------------------
__global__ __launch_bounds__(256) void qkv_gemm_b(
    const __bf16* __restrict__ A, const __bf16* __restrict__ Bt,
    const float* __restrict__ bias,
    __bf16* __restrict__ Qb, __bf16* __restrict__ Kb, __bf16* __restrict__ Vt)
{
  __shared__ alignas(16) __bf16 a_sh[128 * 32];
  __shared__ alignas(16) __bf16 b_sh[128 * 32];
  const int id = blockIdx.x;                    // 1536 wgs
  const int wg = (id & 7) * 192 + (id >> 3);    // bijective XCD swizzle
  const int n0 = (wg % 24) * 128, m0 = (wg / 24) * 128;
  const int t = threadIdx.x, wave = t >> 6, lane = t & 63;
  const int r = lane & 15, g = lane >> 4;
  const int wm = (wave >> 1) * 64, wn = (wave & 1) * 64;
  f32x4 acc[4][4] = {};

  const int srow = wave * 16 + (lane >> 2);
  const int scol = (lane & 3) * 8;
  const __bf16* gA = A + (size_t)(m0 + srow) * 1024 + scol;
  const __bf16* gB = Bt + (size_t)(n0 + srow) * 1024 + scol;
  __bf16* lA = a_sh + wave * 512;
  __bf16* lB = b_sh + wave * 512;

  for (int k0 = 0; k0 < 1024; k0 += 32) {
    __syncthreads();
    gload16(gA + k0, lA);
    gload16(gA + 64 * 1024 + k0, lA + 2048);
    gload16(gB + k0, lB);
    gload16(gB + 64 * 1024 + k0, lB + 2048);
    __syncthreads();
    bf16x8 af[4], bfr[4];
    #pragma unroll
    for (int i = 0; i < 4; ++i)
      af[i] = *(bf16x8*)&a_sh[(wm + i * 16 + r) * 32 + g * 8];
    #pragma unroll
    for (int j = 0; j < 4; ++j)
      bfr[j] = *(bf16x8*)&b_sh[(wn + j * 16 + r) * 32 + g * 8];
    #pragma unroll
    for (int i = 0; i < 4; ++i)
      #pragma unroll
      for (int j = 0; j < 4; ++j)
        acc[i][j] = MFMA16(af[i], bfr[j], acc[i][j]);
  }

  const int which = n0 >> 10;  // 0=Q 1=K 2=V
  const int bb = m0 >> 11;
  const int sbase = (m0 & 2047) + wm;
  #pragma unroll
  for (int j = 0; j < 4; ++j) {
    const int nc = n0 + wn + j * 16 + r;
    const float bv = bias[nc];
    const int hh = (nc & 1023) >> 6;
    const int d = nc & 63;
    #pragma unroll
    for (int i = 0; i < 4; ++i) {
      const int ss0 = sbase + i * 16 + g * 4;
      if (which == 0) {
        #pragma unroll
        for (int rr = 0; rr < 4; ++rr)
          Qb[((size_t)(bb * 16 + hh) * 2048 + ss0 + rr) * 64 + d] =
              (__bf16)((acc[i][j][rr] + bv) * SCQ);
      } else if (which == 1) {
        #pragma unroll
        for (int rr = 0; rr < 4; ++rr)
          Kb[((size_t)(bb * 16 + hh) * 2048 + ss0 + rr) * 64 + d] =
              (__bf16)(acc[i][j][rr] + bv);
      } else {
        bf16x4 vv;
        #pragma unroll
        for (int rr = 0; rr < 4; ++rr) vv[rr] = (__bf16)(acc[i][j][rr] + bv);
        const int v5 = ss0 & 31;  // multiple of 4
        const int pcol = (ss0 & ~31) + 8 * ((v5 >> 2) & 3) + 4 * (v5 >> 4);
        *(bf16x4*)&Vt[((size_t)(bb * 16 + hh) * 64 + d) * 2048 + pcol] = vv;
      }
    }
  }
}

__global__ __launch_bounds__(256) void proj_gemm_b(
    const __bf16* __restrict__ A, const __bf16* __restrict__ Bt,
    const float* __restrict__ bias, float* __restrict__ out)
{
  __shared__ alignas(16) __bf16 a_sh[128 * 32];
  __shared__ alignas(16) __bf16 b_sh[128 * 32];
  const int id = blockIdx.x;                    // 512 wgs
  const int wg = (id & 7) * 64 + (id >> 3);     // bijective XCD swizzle
  const int n0 = (wg & 7) * 128, m0 = (wg >> 3) * 128;
  const int t = threadIdx.x, wave = t >> 6, lane = t & 63;
  const int r = lane & 15, g = lane >> 4;
  const int wm = (wave >> 1) * 64, wn = (wave & 1) * 64;
  f32x4 acc[4][4] = {};

  const int srow = wave * 16 + (lane >> 2);
  const int scol = (lane & 3) * 8;
  const __bf16* gA = A + (size_t)(m0 + srow) * 1024 + scol;
  const __bf16* gB = Bt + (size_t)(n0 + srow) * 1024 + scol;
  __bf16* lA = a_sh + wave * 512;
  __bf16* lB = b_sh + wave * 512;

  for (int k0 = 0; k0 < 1024; k0 += 32) {
    __syncthreads();
    gload16(gA + k0, lA);
    gload16(gA + 64 * 1024 + k0, lA + 2048);
    gload16(gB + k0, lB);
    gload16(gB + 64 * 1024 + k0, lB + 2048);
    __syncthreads();
    bf16x8 af[4], bfr[4];
    #pragma unroll
    for (int i = 0; i < 4; ++i)
      af[i] = *(bf16x8*)&a_sh[(wm + i * 16 + r) * 32 + g * 8];
    #pragma unroll
    for (int j = 0; j < 4; ++j)
      bfr[j] = *(bf16x8*)&b_sh[(wn + j * 16 + r) * 32 + g * 8];
    #pragma unroll
    for (int i = 0; i < 4; ++i)
      #pragma unroll
      for (int j = 0; j < 4; ++j)
        acc[i][j] = MFMA16(af[i], bfr[j], acc[i][j]);
  }

  #pragma unroll
  for (int j = 0; j < 4; ++j) {
    const int nc = n0 + wn + j * 16 + r;
    const float bv = bias[nc];
    #pragma unroll
    for (int i = 0; i < 4; ++i)
      #pragma unroll
      for (int rr = 0; rr < 4; ++rr)
        out[(size_t)(m0 + wm + i * 16 + g * 4 + rr) * 1024 + nc] =
            acc[i][j][rr] + bv;
  }
}

// ---------------------------------------------------------------------------
// Flash attention v7 = r6/r7 structure + softmax instruction diet:
// v_cvt_pk_bf16_f32 packing (16 insts vs ~128 scalar-cvt VALU ops) and
// tree-structured sums (depth 4 vs 16-deep serial chain).
// ---------------------------------------------------------------------------
__global__ __launch_bounds__(256, 4) void attn_kernel(
    const __bf16* __restrict__ Q, const __bf16* __restrict__ K,
    const __bf16* __restrict__ Vt, __bf16* __restrict__ AO)
{
  __shared__ alignas(16) __bf16 k_sh[64][72];
  __shared__ alignas(16) __bf16 v_sh[64][72];

  const int p = blockIdx.x;
  const int hd = (p & 7) + 8 * (p >> 7);   // head linear = b*16+h; 8 heads/XCD
  const int qt = (p >> 3) & 15;
  const int b = hd >> 4, h = hd & 15;

  const int t = threadIdx.x, wave = t >> 6, lane = t & 63;
  const int r = lane & 15, g = lane >> 4;

  const __bf16* Qp = Q + (size_t)hd * (2048 * 64);
  const __bf16* Kp = K + (size_t)hd * (2048 * 64);
  const __bf16* Vp = Vt + (size_t)hd * (64 * 2048);
  const int q0 = qt * 128 + wave * 32;

  // staging map: thread t covers row sr = t>>2, element cols sc, sc+32
  const int sr = t >> 2;
  const int sc = (t & 3) * 8;
  const __bf16* gK = Kp + (size_t)sr * 64 + sc;
  const __bf16* gV = Vp + (size_t)sr * 2048 + sc;

  // Q fragments (pre-scaled by SCQ at QKV epilogue)
  bf16x8 qf[2][2];
  #pragma unroll
  for (int qh = 0; qh < 2; ++qh)
    #pragma unroll
    for (int hh = 0; hh < 2; ++hh)
      qf[qh][hh] =
          *(const bf16x8*)(Qp + (size_t)(q0 + qh * 16 + r) * 64 + hh * 32 + g * 8);

  float mrun[2] = {0.f, 0.f};
  float lrun[2] = {0.f, 0.f};   // lane-partial; reduced once in epilogue
  f32x4 o[4][2] = {};

  bf16x8 rk0, rk1, rv0, rv1;    // staged regs (T14)
  #define LOADT(kk)                                                \
    {                                                              \
      rk0 = *(const bf16x8*)(gK + (size_t)(kk) * 64);              \
      rk1 = *(const bf16x8*)(gK + (size_t)(kk) * 64 + 32);         \
      rv0 = *(const bf16x8*)(gV + (kk));                           \
      rv1 = *(const bf16x8*)(gV + (kk) + 32);                      \
    }

  LOADT(0);

  for (int t32 = 0; t32 < 32; ++t32) {
    __syncthreads();   // previous tile's LDS reads complete
    *(bf16x8*)&k_sh[sr][sc] = rk0;
    *(bf16x8*)&k_sh[sr][sc + 32] = rk1;
    *(bf16x8*)&v_sh[sr][sc] = rv0;
    *(bf16x8*)&v_sh[sr][sc + 32] = rv1;
    __syncthreads();
    if (t32 < 31) LOADT((t32 + 1) * 64);   // prefetch; hides under compute

    // --- QK^T (swapped): sacc[kt][qh] = S_log2[k=16kt+4g+rr][q=r] - m ---
    f32x4 sacc[4][2];
    const f32x4 seed0 = {-mrun[0], -mrun[0], -mrun[0], -mrun[0]};
    const f32x4 seed1 = {-mrun[1], -mrun[1], -mrun[1], -mrun[1]};
    __builtin_amdgcn_s_setprio(1);
    #pragma unroll
    for (int kt = 0; kt < 4; ++kt) {
      const bf16x8 kf0 = *(const bf16x8*)&k_sh[kt * 16 + r][g * 8];
      const bf16x8 kf1 = *(const bf16x8*)&k_sh[kt * 16 + r][32 + g * 8];
      f32x4 s0 = MFMA16(kf0, qf[0][0], seed0);
      s0 = MFMA16(kf1, qf[0][1], s0);
      sacc[kt][0] = s0;
      f32x4 s1 = MFMA16(kf0, qf[1][0], seed1);
      s1 = MFMA16(kf1, qf[1][1], s1);
      sacc[kt][1] = s1;
    }
    __builtin_amdgcn_s_setprio(0);

    // --- softmax: defer-max; exp2 into static e[][]; tree sum; pk-pack ---
    bf16x8 pf[2][2];
    #pragma unroll
    for (int qh = 0; qh < 2; ++qh) {
      float a0 = fmaxf(fmaxf(sacc[0][qh][0], sacc[0][qh][1]),
                       fmaxf(sacc[0][qh][2], sacc[0][qh][3]));
      float a1 = fmaxf(fmaxf(sacc[1][qh][0], sacc[1][qh][1]),
                       fmaxf(sacc[1][qh][2], sacc[1][qh][3]));
      float a2 = fmaxf(fmaxf(sacc[2][qh][0], sacc[2][qh][1]),
                       fmaxf(sacc[2][qh][2], sacc[2][qh][3]));
      float a3 = fmaxf(fmaxf(sacc[3][qh][0], sacc[3][qh][1]),
                       fmaxf(sacc[3][qh][2], sacc[3][qh][3]));
      const float tm = fmaxf(fmaxf(a0, a1), fmaxf(a2, a3));  // lane-local

      float e[4][4];
      if (__any(tm > 6.0f)) {        // rare path: true rescale
        float rm = fmaxf(tm, __shfl_xor(tm, 16));
        rm = fmaxf(rm, __shfl_xor(rm, 32));
        const float dl = fmaxf(rm, 0.f);
        const float al = exp2f(-dl);
        mrun[qh] += dl;
        #pragma unroll
        for (int kt = 0; kt < 4; ++kt)
          #pragma unroll
          for (int rr = 0; rr < 4; ++rr)
            e[kt][rr] = exp2f(sacc[kt][qh][rr] - dl);
        lrun[qh] *= al;
        #pragma unroll
        for (int dt = 0; dt < 4; ++dt)
          #pragma unroll
          for (int rr = 0; rr < 4; ++rr)
            o[dt][qh][rr] *= al;
      } else {                        // common path
        #pragma unroll
        for (int kt = 0; kt < 4; ++kt)
          #pragma unroll
          for (int rr = 0; rr < 4; ++rr)
            e[kt][rr] = exp2f(sacc[kt][qh][rr]);
      }
      // tree sum (depth 4)
      const float s0 = (e[0][0] + e[0][1]) + (e[0][2] + e[0][3]);
      const float s1 = (e[1][0] + e[1][1]) + (e[1][2] + e[1][3]);
      const float s2 = (e[2][0] + e[2][1]) + (e[2][2] + e[2][3]);
      const float s3 = (e[3][0] + e[3][1]) + (e[3][2] + e[3][3]);
      lrun[qh] += (s0 + s1) + (s2 + s3);
      // pack via v_cvt_pk_bf16_f32 (RNE, 1 inst / 2 values)
      uint32x4 u0 = {cvtpk(e[0][0], e[0][1]), cvtpk(e[0][2], e[0][3]),
                     cvtpk(e[1][0], e[1][1]), cvtpk(e[1][2], e[1][3])};
      uint32x4 u1 = {cvtpk(e[2][0], e[2][1]), cvtpk(e[2][2], e[2][3]),
                     cvtpk(e[3][0], e[3][1]), cvtpk(e[3][2], e[3][3])};
      pf[qh][0] = __builtin_bit_cast(bf16x8, u0);
      pf[qh][1] = __builtin_bit_cast(bf16x8, u1);
    }

    // --- PV: A = V (sigma-ordered cols), B = P (same order) ---
    __builtin_amdgcn_s_setprio(1);
    #pragma unroll
    for (int c = 0; c < 2; ++c)
      #pragma unroll
      for (int dt = 0; dt < 4; ++dt) {
        const bf16x8 vf = *(const bf16x8*)&v_sh[dt * 16 + r][c * 32 + g * 8];
        o[dt][0] = MFMA16(vf, pf[0][c], o[dt][0]);
        o[dt][1] = MFMA16(vf, pf[1][c], o[dt][1]);
      }
    __builtin_amdgcn_s_setprio(0);
  }
  #undef LOADT

  // --- epilogue: reduce lrun across g-groups once, normalize, write ---
  #pragma unroll
  for (int qh = 0; qh < 2; ++qh) {
    float lr = lrun[qh];
    lr += __shfl_xor(lr, 16);
    lr += __shfl_xor(lr, 32);
    const float inv = 1.0f / lr;
    const int ss = q0 + qh * 16 + r;
    #pragma unroll
    for (int dt = 0; dt < 4; ++dt) {
      bf16x4 ov;
      #pragma unroll
      for (int rr = 0; rr < 4; ++rr)
        ov[rr] = (__bf16)(o[dt][qh][rr] * inv);
      *(bf16x4*)&AO[((size_t)b * 2048 + ss) * 1024 + h * 64 + dt * 16 + 4 * g] = ov;
    }
  }
}

// ---------------------------------------------------------------------------
extern "C" void kernel_launch(void* const* d_in, const int* in_sizes, int n_in,
                              void* d_out, int out_size, void* d_ws, size_t ws_size,
                              hipStream_t stream) {
  (void)in_sizes; (void)n_in; (void)out_size; (void)ws_size;
  const float* x      = (const float*)d_in[0];
  const float* w_qkv  = (const float*)d_in[1];
  const float* b_qkv  = (const float*)d_in[2];
  const float* w_proj = (const float*)d_in[3];
  const float* b_proj = (const float*)d_in[4];
  float* out = (float*)d_out;

  char* ws = (char*)d_ws;
  const size_t E2 = (size_t)8192 * 1024 * 2;  // bytes per [8192][1024] bf16
  __bf16* Qb  = (__bf16*)(ws);
  __bf16* Kb  = (__bf16*)(ws + E2);
  __bf16* Vt  = (__bf16*)(ws + 2 * E2);
  __bf16* Xb  = (__bf16*)(ws + 3 * E2);
  __bf16* AO  = Xb;  // Xb dead after qkv_gemm_b; reuse for attention output
  __bf16* Wqt = (__bf16*)(ws + 4 * E2);
  __bf16* Wpt = (__bf16*)(ws + 4 * E2 + (size_t)3072 * 1024 * 2);

  conv_x<<<4096, 256, 0, stream>>>(x, Xb);
  conv_wt<<<dim3(48, 16), 256, 0, stream>>>(w_qkv, Wqt, 1024, 3072);
  conv_wt<<<dim3(16, 16), 256, 0, stream>>>(w_proj, Wpt, 1024, 1024);
  qkv_gemm_b<<<1536, 256, 0, stream>>>(Xb, Wqt, b_qkv, Qb, Kb, Vt);
  attn_kernel<<<1024, 256, 0, stream>>>(Qb, Kb, Vt, AO);
  proj_gemm_b<<<512, 256, 0, stream>>>(AO, Wpt, b_proj, out);
}

// Round 9
// 318.693 us; speedup vs baseline: 1.1377x; 1.1377x over previous
//
#include <hip/hip_runtime.h>
#include <hip/hip_bf16.h>
#include <cstdint>

typedef __attribute__((ext_vector_type(8))) __bf16 bf16x8;
typedef __attribute__((ext_vector_type(4))) __bf16 bf16x4;
typedef __attribute__((ext_vector_type(4))) float f32x4;

#define MFMA16(a, b, c) __builtin_amdgcn_mfma_f32_16x16x32_bf16(a, b, c, 0, 0, 0)

static constexpr float SCQ = 0.18033688f;  // (1/sqrt(64)) * log2(e)

__device__ __forceinline__ void gload16(const void* g, void* l) {
  __builtin_amdgcn_global_load_lds(
      (const __attribute__((address_space(1))) void*)g,
      (__attribute__((address_space(3))) void*)l, 16, 0, 0);
}

// ---------------------------------------------------------------------------
// conv_x: f32 [8192][1024] -> bf16 same layout
// ---------------------------------------------------------------------------
__global__ __launch_bounds__(256) void conv_x(const float* __restrict__ in,
                                              __bf16* __restrict__ out) {
  const size_t i = ((size_t)blockIdx.x * 256 + threadIdx.x) * 8;
  const float4 v0 = *(const float4*)(in + i);
  const float4 v1 = *(const float4*)(in + i + 4);
  bf16x8 o = {(__bf16)v0.x, (__bf16)v0.y, (__bf16)v0.z, (__bf16)v0.w,
              (__bf16)v1.x, (__bf16)v1.y, (__bf16)v1.z, (__bf16)v1.w};
  *(bf16x8*)(out + i) = o;
}

// ---------------------------------------------------------------------------
// conv_wt: W f32 [K][N] -> Wt bf16 [N][K]  (transpose via LDS tile)
// ---------------------------------------------------------------------------
__global__ __launch_bounds__(256) void conv_wt(const float* __restrict__ W,
                                               __bf16* __restrict__ Wt,
                                               int K, int N) {
  __shared__ float tile[64][65];
  const int nb = blockIdx.x * 64, kb = blockIdx.y * 64;
  const int t = threadIdx.x, tr = t >> 4, tc = t & 15;
  #pragma unroll
  for (int p = 0; p < 4; ++p) {
    const float4 v =
        *(const float4*)(W + (size_t)(kb + p * 16 + tr) * N + nb + tc * 4);
    tile[p * 16 + tr][tc * 4 + 0] = v.x;
    tile[p * 16 + tr][tc * 4 + 1] = v.y;
    tile[p * 16 + tr][tc * 4 + 2] = v.z;
    tile[p * 16 + tr][tc * 4 + 3] = v.w;
  }
  __syncthreads();
  #pragma unroll
  for (int p = 0; p < 4; ++p) {
    const int n = p * 16 + tr, kk = tc * 4;
    bf16x4 o = {(__bf16)tile[kk + 0][n], (__bf16)tile[kk + 1][n],
                (__bf16)tile[kk + 2][n], (__bf16)tile[kk + 3][n]};
    *(bf16x4*)(Wt + (size_t)(nb + n) * K + kb + kk) = o;
  }
}

// ---------------------------------------------------------------------------
// GEMM core (m97 structure): 128x128 tile, BK=32, global_load_lds w=16,
// linear LDS, flat grid with bijective XCD swizzle (T1).
// V stored sigma-permuted: key s (w=s&31=4a+b) -> col (s&~31)+8*(a&3)+4*(a>>2)+b
// so attention's PV B-fragments are MFMA-lane-ordered.
// ---------------------------------------------------------------------------
__global__ __launch_bounds__(256) void qkv_gemm_b(
    const __bf16* __restrict__ A, const __bf16* __restrict__ Bt,
    const float* __restrict__ bias,
    __bf16* __restrict__ Qb, __bf16* __restrict__ Kb, __bf16* __restrict__ Vt)
{
  __shared__ alignas(16) __bf16 a_sh[128 * 32];
  __shared__ alignas(16) __bf16 b_sh[128 * 32];
  const int id = blockIdx.x;                    // 1536 wgs
  const int wg = (id & 7) * 192 + (id >> 3);    // bijective XCD swizzle
  const int n0 = (wg % 24) * 128, m0 = (wg / 24) * 128;
  const int t = threadIdx.x, wave = t >> 6, lane = t & 63;
  const int r = lane & 15, g = lane >> 4;
  const int wm = (wave >> 1) * 64, wn = (wave & 1) * 64;
  f32x4 acc[4][4] = {};

  const int srow = wave * 16 + (lane >> 2);
  const int scol = (lane & 3) * 8;
  const __bf16* gA = A + (size_t)(m0 + srow) * 1024 + scol;
  const __bf16* gB = Bt + (size_t)(n0 + srow) * 1024 + scol;
  __bf16* lA = a_sh + wave * 512;
  __bf16* lB = b_sh + wave * 512;

  for (int k0 = 0; k0 < 1024; k0 += 32) {
    __syncthreads();
    gload16(gA + k0, lA);
    gload16(gA + 64 * 1024 + k0, lA + 2048);
    gload16(gB + k0, lB);
    gload16(gB + 64 * 1024 + k0, lB + 2048);
    __syncthreads();
    bf16x8 af[4], bfr[4];
    #pragma unroll
    for (int i = 0; i < 4; ++i)
      af[i] = *(bf16x8*)&a_sh[(wm + i * 16 + r) * 32 + g * 8];
    #pragma unroll
    for (int j = 0; j < 4; ++j)
      bfr[j] = *(bf16x8*)&b_sh[(wn + j * 16 + r) * 32 + g * 8];
    #pragma unroll
    for (int i = 0; i < 4; ++i)
      #pragma unroll
      for (int j = 0; j < 4; ++j)
        acc[i][j] = MFMA16(af[i], bfr[j], acc[i][j]);
  }

  const int which = n0 >> 10;  // 0=Q 1=K 2=V
  const int bb = m0 >> 11;
  const int sbase = (m0 & 2047) + wm;
  #pragma unroll
  for (int j = 0; j < 4; ++j) {
    const int nc = n0 + wn + j * 16 + r;
    const float bv = bias[nc];
    const int hh = (nc & 1023) >> 6;
    const int d = nc & 63;
    #pragma unroll
    for (int i = 0; i < 4; ++i) {
      const int ss0 = sbase + i * 16 + g * 4;
      if (which == 0) {
        #pragma unroll
        for (int rr = 0; rr < 4; ++rr)
          Qb[((size_t)(bb * 16 + hh) * 2048 + ss0 + rr) * 64 + d] =
              (__bf16)((acc[i][j][rr] + bv) * SCQ);
      } else if (which == 1) {
        #pragma unroll
        for (int rr = 0; rr < 4; ++rr)
          Kb[((size_t)(bb * 16 + hh) * 2048 + ss0 + rr) * 64 + d] =
              (__bf16)(acc[i][j][rr] + bv);
      } else {
        bf16x4 vv;
        #pragma unroll
        for (int rr = 0; rr < 4; ++rr) vv[rr] = (__bf16)(acc[i][j][rr] + bv);
        const int v5 = ss0 & 31;  // multiple of 4
        const int pcol = (ss0 & ~31) + 8 * ((v5 >> 2) & 3) + 4 * (v5 >> 4);
        *(bf16x4*)&Vt[((size_t)(bb * 16 + hh) * 64 + d) * 2048 + pcol] = vv;
      }
    }
  }
}

__global__ __launch_bounds__(256) void proj_gemm_b(
    const __bf16* __restrict__ A, const __bf16* __restrict__ Bt,
    const float* __restrict__ bias, float* __restrict__ out)
{
  __shared__ alignas(16) __bf16 a_sh[128 * 32];
  __shared__ alignas(16) __bf16 b_sh[128 * 32];
  const int id = blockIdx.x;                    // 512 wgs
  const int wg = (id & 7) * 64 + (id >> 3);     // bijective XCD swizzle
  const int n0 = (wg & 7) * 128, m0 = (wg >> 3) * 128;
  const int t = threadIdx.x, wave = t >> 6, lane = t & 63;
  const int r = lane & 15, g = lane >> 4;
  const int wm = (wave >> 1) * 64, wn = (wave & 1) * 64;
  f32x4 acc[4][4] = {};

  const int srow = wave * 16 + (lane >> 2);
  const int scol = (lane & 3) * 8;
  const __bf16* gA = A + (size_t)(m0 + srow) * 1024 + scol;
  const __bf16* gB = Bt + (size_t)(n0 + srow) * 1024 + scol;
  __bf16* lA = a_sh + wave * 512;
  __bf16* lB = b_sh + wave * 512;

  for (int k0 = 0; k0 < 1024; k0 += 32) {
    __syncthreads();
    gload16(gA + k0, lA);
    gload16(gA + 64 * 1024 + k0, lA + 2048);
    gload16(gB + k0, lB);
    gload16(gB + 64 * 1024 + k0, lB + 2048);
    __syncthreads();
    bf16x8 af[4], bfr[4];
    #pragma unroll
    for (int i = 0; i < 4; ++i)
      af[i] = *(bf16x8*)&a_sh[(wm + i * 16 + r) * 32 + g * 8];
    #pragma unroll
    for (int j = 0; j < 4; ++j)
      bfr[j] = *(bf16x8*)&b_sh[(wn + j * 16 + r) * 32 + g * 8];
    #pragma unroll
    for (int i = 0; i < 4; ++i)
      #pragma unroll
      for (int j = 0; j < 4; ++j)
        acc[i][j] = MFMA16(af[i], bfr[j], acc[i][j]);
  }

  #pragma unroll
  for (int j = 0; j < 4; ++j) {
    const int nc = n0 + wn + j * 16 + r;
    const float bv = bias[nc];
    #pragma unroll
    for (int i = 0; i < 4; ++i)
      #pragma unroll
      for (int rr = 0; rr < 4; ++rr)
        out[(size_t)(m0 + wm + i * 16 + g * 4 + rr) * 1024 + nc] =
            acc[i][j][rr] + bv;
  }
}

// ---------------------------------------------------------------------------
// Flash attention v8 = r7 structure with KVBLK=128: one stage+barrier pair
// per 128 keys (16 iters instead of 32), computed as two sequential 64-key
// softmax passes (identical math/registers).  T14 prefetch of next 128-key
// tile.  Scalar bf16 casts (compiler emits packed cvt; hand asm was -48%).
// ---------------------------------------------------------------------------
__global__ __launch_bounds__(256, 4) void attn_kernel(
    const __bf16* __restrict__ Q, const __bf16* __restrict__ K,
    const __bf16* __restrict__ Vt, __bf16* __restrict__ AO)
{
  __shared__ alignas(16) __bf16 k_sh[128][72];   // 18.4 KB
  __shared__ alignas(16) __bf16 v_sh[64][136];   // 17.4 KB

  const int p = blockIdx.x;
  const int hd = (p & 7) + 8 * (p >> 7);   // head linear = b*16+h; 8 heads/XCD
  const int qt = (p >> 3) & 15;
  const int b = hd >> 4, h = hd & 15;

  const int t = threadIdx.x, wave = t >> 6, lane = t & 63;
  const int r = lane & 15, g = lane >> 4;

  const __bf16* Qp = Q + (size_t)hd * (2048 * 64);
  const __bf16* Kp = K + (size_t)hd * (2048 * 64);
  const __bf16* Vp = Vt + (size_t)hd * (64 * 2048);
  const int q0 = qt * 128 + wave * 32;

  // staging maps (KVBLK=128):
  // K tile 128 keys x 64 d: thread t -> key row kr=t>>1, cols kc+{0,8,16,24}
  const int kr = t >> 1, kc = (t & 1) * 32;
  const __bf16* gK = Kp + (size_t)kr * 64 + kc;
  // V tile 64 d x 128 keys: thread t -> d row vr=t>>2, key cols vc+{0,32,64,96}
  const int vr = t >> 2, vc = (t & 3) * 8;
  const __bf16* gV = Vp + (size_t)vr * 2048 + vc;

  // Q fragments (pre-scaled by SCQ at QKV epilogue)
  bf16x8 qf[2][2];
  #pragma unroll
  for (int qh = 0; qh < 2; ++qh)
    #pragma unroll
    for (int hh = 0; hh < 2; ++hh)
      qf[qh][hh] =
          *(const bf16x8*)(Qp + (size_t)(q0 + qh * 16 + r) * 64 + hh * 32 + g * 8);

  float mrun[2] = {0.f, 0.f};
  float lrun[2] = {0.f, 0.f};   // lane-partial; reduced once in epilogue
  f32x4 o[4][2] = {};

  bf16x8 rk0, rk1, rk2, rk3, rv0, rv1, rv2, rv3;   // staged regs (T14)
  #define LOADT(kk)                                               \
    {                                                             \
      rk0 = *(const bf16x8*)(gK + (size_t)(kk) * 64);             \
      rk1 = *(const bf16x8*)(gK + (size_t)(kk) * 64 + 8);         \
      rk2 = *(const bf16x8*)(gK + (size_t)(kk) * 64 + 16);        \
      rk3 = *(const bf16x8*)(gK + (size_t)(kk) * 64 + 24);        \
      rv0 = *(const bf16x8*)(gV + (kk));                          \
      rv1 = *(const bf16x8*)(gV + (kk) + 32);                     \
      rv2 = *(const bf16x8*)(gV + (kk) + 64);                     \
      rv3 = *(const bf16x8*)(gV + (kk) + 96);                     \
    }

  LOADT(0);

  for (int t16 = 0; t16 < 16; ++t16) {
    __syncthreads();   // previous tile's LDS reads complete
    *(bf16x8*)&k_sh[kr][kc] = rk0;
    *(bf16x8*)&k_sh[kr][kc + 8] = rk1;
    *(bf16x8*)&k_sh[kr][kc + 16] = rk2;
    *(bf16x8*)&k_sh[kr][kc + 24] = rk3;
    *(bf16x8*)&v_sh[vr][vc] = rv0;
    *(bf16x8*)&v_sh[vr][vc + 32] = rv1;
    *(bf16x8*)&v_sh[vr][vc + 64] = rv2;
    *(bf16x8*)&v_sh[vr][vc + 96] = rv3;
    __syncthreads();
    if (t16 < 15) LOADT((t16 + 1) * 128);   // prefetch; hides under compute

    #pragma unroll
    for (int half = 0; half < 2; ++half) {
      // --- QK^T (swapped): sacc[kt][qh] = S_log2[k][q=r] - m ---
      f32x4 sacc[4][2];
      const f32x4 seed0 = {-mrun[0], -mrun[0], -mrun[0], -mrun[0]};
      const f32x4 seed1 = {-mrun[1], -mrun[1], -mrun[1], -mrun[1]};
      __builtin_amdgcn_s_setprio(1);
      #pragma unroll
      for (int kt = 0; kt < 4; ++kt) {
        const bf16x8 kf0 = *(const bf16x8*)&k_sh[half * 64 + kt * 16 + r][g * 8];
        const bf16x8 kf1 =
            *(const bf16x8*)&k_sh[half * 64 + kt * 16 + r][32 + g * 8];
        f32x4 s0 = MFMA16(kf0, qf[0][0], seed0);
        s0 = MFMA16(kf1, qf[0][1], s0);
        sacc[kt][0] = s0;
        f32x4 s1 = MFMA16(kf0, qf[1][0], seed1);
        s1 = MFMA16(kf1, qf[1][1], s1);
        sacc[kt][1] = s1;
      }
      __builtin_amdgcn_s_setprio(0);

      // --- softmax: defer-max, fused exp2+sum+cvt into pf ---
      bf16x8 pf[2][2];
      #pragma unroll
      for (int qh = 0; qh < 2; ++qh) {
        float a0 = fmaxf(fmaxf(sacc[0][qh][0], sacc[0][qh][1]),
                         fmaxf(sacc[0][qh][2], sacc[0][qh][3]));
        float a1 = fmaxf(fmaxf(sacc[1][qh][0], sacc[1][qh][1]),
                         fmaxf(sacc[1][qh][2], sacc[1][qh][3]));
        float a2 = fmaxf(fmaxf(sacc[2][qh][0], sacc[2][qh][1]),
                         fmaxf(sacc[2][qh][2], sacc[2][qh][3]));
        float a3 = fmaxf(fmaxf(sacc[3][qh][0], sacc[3][qh][1]),
                         fmaxf(sacc[3][qh][2], sacc[3][qh][3]));
        const float tm = fmaxf(fmaxf(a0, a1), fmaxf(a2, a3));  // lane-local

        float s = 0.f;
        if (__any(tm > 6.0f)) {        // rare path: true rescale
          float rm = fmaxf(tm, __shfl_xor(tm, 16));
          rm = fmaxf(rm, __shfl_xor(rm, 32));
          const float dl = fmaxf(rm, 0.f);
          const float al = exp2f(-dl);
          mrun[qh] += dl;
          #pragma unroll
          for (int kt = 0; kt < 4; ++kt)
            #pragma unroll
            for (int rr = 0; rr < 4; ++rr) {
              const float e = exp2f(sacc[kt][qh][rr] - dl);
              s += e;
              pf[qh][kt >> 1][(kt & 1) * 4 + rr] = (__bf16)e;
            }
          lrun[qh] = lrun[qh] * al + s;
          #pragma unroll
          for (int dt = 0; dt < 4; ++dt)
            #pragma unroll
            for (int rr = 0; rr < 4; ++rr)
              o[dt][qh][rr] *= al;
        } else {                        // common path: zero cross-lane ops
          #pragma unroll
          for (int kt = 0; kt < 4; ++kt)
            #pragma unroll
            for (int rr = 0; rr < 4; ++rr) {
              const float e = exp2f(sacc[kt][qh][rr]);
              s += e;
              pf[qh][kt >> 1][(kt & 1) * 4 + rr] = (__bf16)e;
            }
          lrun[qh] += s;
        }
      }

      // --- PV: A = V (sigma-ordered cols), B = P (same order) ---
      __builtin_amdgcn_s_setprio(1);
      #pragma unroll
      for (int c = 0; c < 2; ++c)
        #pragma unroll
        for (int dt = 0; dt < 4; ++dt) {
          const bf16x8 vf =
              *(const bf16x8*)&v_sh[dt * 16 + r][half * 64 + c * 32 + g * 8];
          o[dt][0] = MFMA16(vf, pf[0][c], o[dt][0]);
          o[dt][1] = MFMA16(vf, pf[1][c], o[dt][1]);
        }
      __builtin_amdgcn_s_setprio(0);
    }
  }
  #undef LOADT

  // --- epilogue: reduce lrun across g-groups once, normalize, write ---
  #pragma unroll
  for (int qh = 0; qh < 2; ++qh) {
    float lr = lrun[qh];
    lr += __shfl_xor(lr, 16);
    lr += __shfl_xor(lr, 32);
    const float inv = 1.0f / lr;
    const int ss = q0 + qh * 16 + r;
    #pragma unroll
    for (int dt = 0; dt < 4; ++dt) {
      bf16x4 ov;
      #pragma unroll
      for (int rr = 0; rr < 4; ++rr)
        ov[rr] = (__bf16)(o[dt][qh][rr] * inv);
      *(bf16x4*)&AO[((size_t)b * 2048 + ss) * 1024 + h * 64 + dt * 16 + 4 * g] = ov;
    }
  }
}

// ---------------------------------------------------------------------------
extern "C" void kernel_launch(void* const* d_in, const int* in_sizes, int n_in,
                              void* d_out, int out_size, void* d_ws, size_t ws_size,
                              hipStream_t stream) {
  (void)in_sizes; (void)n_in; (void)out_size; (void)ws_size;
  const float* x      = (const float*)d_in[0];
  const float* w_qkv  = (const float*)d_in[1];
  const float* b_qkv  = (const float*)d_in[2];
  const float* w_proj = (const float*)d_in[3];
  const float* b_proj = (const float*)d_in[4];
  float* out = (float*)d_out;

  char* ws = (char*)d_ws;
  const size_t E2 = (size_t)8192 * 1024 * 2;  // bytes per [8192][1024] bf16
  __bf16* Qb  = (__bf16*)(ws);
  __bf16* Kb  = (__bf16*)(ws + E2);
  __bf16* Vt  = (__bf16*)(ws + 2 * E2);
  __bf16* Xb  = (__bf16*)(ws + 3 * E2);
  __bf16* AO  = Xb;  // Xb dead after qkv_gemm_b; reuse for attention output
  __bf16* Wqt = (__bf16*)(ws + 4 * E2);
  __bf16* Wpt = (__bf16*)(ws + 4 * E2 + (size_t)3072 * 1024 * 2);

  conv_x<<<4096, 256, 0, stream>>>(x, Xb);
  conv_wt<<<dim3(48, 16), 256, 0, stream>>>(w_qkv, Wqt, 1024, 3072);
  conv_wt<<<dim3(16, 16), 256, 0, stream>>>(w_proj, Wpt, 1024, 1024);
  qkv_gemm_b<<<1536, 256, 0, stream>>>(Xb, Wqt, b_qkv, Qb, Kb, Vt);
  attn_kernel<<<1024, 256, 0, stream>>>(Qb, Kb, Vt, AO);
  proj_gemm_b<<<512, 256, 0, stream>>>(AO, Wpt, b_proj, out);
}

// Round 10
// 245.585 us; speedup vs baseline: 1.4764x; 1.2977x over previous
//
#include <hip/hip_runtime.h>
#include <hip/hip_bf16.h>
#include <cstdint>

typedef __attribute__((ext_vector_type(8))) __bf16 bf16x8;
typedef __attribute__((ext_vector_type(4))) __bf16 bf16x4;
typedef __attribute__((ext_vector_type(4))) float f32x4;

#define MFMA16(a, b, c) __builtin_amdgcn_mfma_f32_16x16x32_bf16(a, b, c, 0, 0, 0)

static constexpr float SCQ = 0.18033688f;  // (1/sqrt(64)) * log2(e)

__device__ __forceinline__ void gload16(const void* g, void* l) {
  __builtin_amdgcn_global_load_lds(
      (const __attribute__((address_space(1))) void*)g,
      (__attribute__((address_space(3))) void*)l, 16, 0, 0);
}

// ---------------------------------------------------------------------------
// conv_x: f32 [8192][1024] -> bf16 same layout
// ---------------------------------------------------------------------------
__global__ __launch_bounds__(256) void conv_x(const float* __restrict__ in,
                                              __bf16* __restrict__ out) {
  const size_t i = ((size_t)blockIdx.x * 256 + threadIdx.x) * 8;
  const float4 v0 = *(const float4*)(in + i);
  const float4 v1 = *(const float4*)(in + i + 4);
  bf16x8 o = {(__bf16)v0.x, (__bf16)v0.y, (__bf16)v0.z, (__bf16)v0.w,
              (__bf16)v1.x, (__bf16)v1.y, (__bf16)v1.z, (__bf16)v1.w};
  *(bf16x8*)(out + i) = o;
}

// ---------------------------------------------------------------------------
// conv_wt: W f32 [K][N] -> Wt bf16 [N][K]  (transpose via LDS tile)
// ---------------------------------------------------------------------------
__global__ __launch_bounds__(256) void conv_wt(const float* __restrict__ W,
                                               __bf16* __restrict__ Wt,
                                               int K, int N) {
  __shared__ float tile[64][65];
  const int nb = blockIdx.x * 64, kb = blockIdx.y * 64;
  const int t = threadIdx.x, tr = t >> 4, tc = t & 15;
  #pragma unroll
  for (int p = 0; p < 4; ++p) {
    const float4 v =
        *(const float4*)(W + (size_t)(kb + p * 16 + tr) * N + nb + tc * 4);
    tile[p * 16 + tr][tc * 4 + 0] = v.x;
    tile[p * 16 + tr][tc * 4 + 1] = v.y;
    tile[p * 16 + tr][tc * 4 + 2] = v.z;
    tile[p * 16 + tr][tc * 4 + 3] = v.w;
  }
  __syncthreads();
  #pragma unroll
  for (int p = 0; p < 4; ++p) {
    const int n = p * 16 + tr, kk = tc * 4;
    bf16x4 o = {(__bf16)tile[kk + 0][n], (__bf16)tile[kk + 1][n],
                (__bf16)tile[kk + 2][n], (__bf16)tile[kk + 3][n]};
    *(bf16x4*)(Wt + (size_t)(nb + n) * K + kb + kk) = o;
  }
}

// ---------------------------------------------------------------------------
// GEMM core (m97 structure): 128x128 tile, BK=32, global_load_lds w=16,
// linear LDS, flat grid with bijective XCD swizzle (T1).
// K and Vt are stored XOR-SWIZZLED within each 128B row (elem ^= (row&7)<<3)
// so attention can stage them with global_load_lds into linear LDS and read
// conflict-free (m201 pattern).  V additionally sigma-permuted per 32-block:
// key s (w=s&31=4a+b) -> col (s&~31)+8*(a&3)+4*(a>>2)+b  (MFMA lane order).
// ---------------------------------------------------------------------------
__global__ __launch_bounds__(256) void qkv_gemm_b(
    const __bf16* __restrict__ A, const __bf16* __restrict__ Bt,
    const float* __restrict__ bias,
    __bf16* __restrict__ Qb, __bf16* __restrict__ Kb, __bf16* __restrict__ Vt)
{
  __shared__ alignas(16) __bf16 a_sh[128 * 32];
  __shared__ alignas(16) __bf16 b_sh[128 * 32];
  const int id = blockIdx.x;                    // 1536 wgs
  const int wg = (id & 7) * 192 + (id >> 3);    // bijective XCD swizzle
  const int n0 = (wg % 24) * 128, m0 = (wg / 24) * 128;
  const int t = threadIdx.x, wave = t >> 6, lane = t & 63;
  const int r = lane & 15, g = lane >> 4;
  const int wm = (wave >> 1) * 64, wn = (wave & 1) * 64;
  f32x4 acc[4][4] = {};

  const int srow = wave * 16 + (lane >> 2);
  const int scol = (lane & 3) * 8;
  const __bf16* gA = A + (size_t)(m0 + srow) * 1024 + scol;
  const __bf16* gB = Bt + (size_t)(n0 + srow) * 1024 + scol;
  __bf16* lA = a_sh + wave * 512;
  __bf16* lB = b_sh + wave * 512;

  for (int k0 = 0; k0 < 1024; k0 += 32) {
    __syncthreads();
    gload16(gA + k0, lA);
    gload16(gA + 64 * 1024 + k0, lA + 2048);
    gload16(gB + k0, lB);
    gload16(gB + 64 * 1024 + k0, lB + 2048);
    __syncthreads();
    bf16x8 af[4], bfr[4];
    #pragma unroll
    for (int i = 0; i < 4; ++i)
      af[i] = *(bf16x8*)&a_sh[(wm + i * 16 + r) * 32 + g * 8];
    #pragma unroll
    for (int j = 0; j < 4; ++j)
      bfr[j] = *(bf16x8*)&b_sh[(wn + j * 16 + r) * 32 + g * 8];
    #pragma unroll
    for (int i = 0; i < 4; ++i)
      #pragma unroll
      for (int j = 0; j < 4; ++j)
        acc[i][j] = MFMA16(af[i], bfr[j], acc[i][j]);
  }

  const int which = n0 >> 10;  // 0=Q 1=K 2=V
  const int bb = m0 >> 11;
  const int sbase = (m0 & 2047) + wm;
  #pragma unroll
  for (int j = 0; j < 4; ++j) {
    const int nc = n0 + wn + j * 16 + r;
    const float bv = bias[nc];
    const int hh = (nc & 1023) >> 6;
    const int d = nc & 63;
    #pragma unroll
    for (int i = 0; i < 4; ++i) {
      const int ss0 = sbase + i * 16 + g * 4;
      if (which == 0) {
        #pragma unroll
        for (int rr = 0; rr < 4; ++rr)
          Qb[((size_t)(bb * 16 + hh) * 2048 + ss0 + rr) * 64 + d] =
              (__bf16)((acc[i][j][rr] + bv) * SCQ);
      } else if (which == 1) {
        // K: XOR-swizzled column within the 64-elem row
        #pragma unroll
        for (int rr = 0; rr < 4; ++rr)
          Kb[((size_t)(bb * 16 + hh) * 2048 + ss0 + rr) * 64 +
             (d ^ ((((ss0 + rr) & 7)) << 3))] =
              (__bf16)(acc[i][j][rr] + bv);
      } else {
        bf16x4 vv;
        #pragma unroll
        for (int rr = 0; rr < 4; ++rr) vv[rr] = (__bf16)(acc[i][j][rr] + bv);
        const int v5 = ss0 & 31;  // multiple of 4
        const int pcol = (ss0 & ~31) + 8 * ((v5 >> 2) & 3) + 4 * (v5 >> 4);
        const int scol2 = (pcol & ~127) | ((pcol & 127) ^ ((d & 7) << 3));
        *(bf16x4*)&Vt[((size_t)(bb * 16 + hh) * 64 + d) * 2048 + scol2] = vv;
      }
    }
  }
}

__global__ __launch_bounds__(256) void proj_gemm_b(
    const __bf16* __restrict__ A, const __bf16* __restrict__ Bt,
    const float* __restrict__ bias, float* __restrict__ out)
{
  __shared__ alignas(16) __bf16 a_sh[128 * 32];
  __shared__ alignas(16) __bf16 b_sh[128 * 32];
  const int id = blockIdx.x;                    // 512 wgs
  const int wg = (id & 7) * 64 + (id >> 3);     // bijective XCD swizzle
  const int n0 = (wg & 7) * 128, m0 = (wg >> 3) * 128;
  const int t = threadIdx.x, wave = t >> 6, lane = t & 63;
  const int r = lane & 15, g = lane >> 4;
  const int wm = (wave >> 1) * 64, wn = (wave & 1) * 64;
  f32x4 acc[4][4] = {};

  const int srow = wave * 16 + (lane >> 2);
  const int scol = (lane & 3) * 8;
  const __bf16* gA = A + (size_t)(m0 + srow) * 1024 + scol;
  const __bf16* gB = Bt + (size_t)(n0 + srow) * 1024 + scol;
  __bf16* lA = a_sh + wave * 512;
  __bf16* lB = b_sh + wave * 512;

  for (int k0 = 0; k0 < 1024; k0 += 32) {
    __syncthreads();
    gload16(gA + k0, lA);
    gload16(gA + 64 * 1024 + k0, lA + 2048);
    gload16(gB + k0, lB);
    gload16(gB + 64 * 1024 + k0, lB + 2048);
    __syncthreads();
    bf16x8 af[4], bfr[4];
    #pragma unroll
    for (int i = 0; i < 4; ++i)
      af[i] = *(bf16x8*)&a_sh[(wm + i * 16 + r) * 32 + g * 8];
    #pragma unroll
    for (int j = 0; j < 4; ++j)
      bfr[j] = *(bf16x8*)&b_sh[(wn + j * 16 + r) * 32 + g * 8];
    #pragma unroll
    for (int i = 0; i < 4; ++i)
      #pragma unroll
      for (int j = 0; j < 4; ++j)
        acc[i][j] = MFMA16(af[i], bfr[j], acc[i][j]);
  }

  #pragma unroll
  for (int j = 0; j < 4; ++j) {
    const int nc = n0 + wn + j * 16 + r;
    const float bv = bias[nc];
    #pragma unroll
    for (int i = 0; i < 4; ++i)
      #pragma unroll
      for (int rr = 0; rr < 4; ++rr)
        out[(size_t)(m0 + wm + i * 16 + g * 4 + rr) * 1024 + nc] =
            acc[i][j][rr] + bv;
  }
}

// ---------------------------------------------------------------------------
// Flash attention v9 = v5 math + gload_lds staging:
// K/V stored XOR-swizzled in global; staged by 4 global_load_lds(16B)/thread
// into linear double-buffered LDS (zero staging VALU, zero write conflicts);
// ONE barrier per 64-key tile (next tile's loads in flight during compute,
// drained by the barrier's vmcnt).  Reads XOR back -> 2-way conflicts (free).
// Swapped QK^T, C seeded with -m, defer-max, lane-local sigma-ordered P.
// ---------------------------------------------------------------------------
__global__ __launch_bounds__(256, 4) void attn_kernel(
    const __bf16* __restrict__ Q, const __bf16* __restrict__ K,
    const __bf16* __restrict__ Vt, __bf16* __restrict__ AO)
{
  __shared__ alignas(16) char lds[2][16384];   // [buf][ K 8KB | V 8KB ]

  const int p = blockIdx.x;
  const int hd = (p & 7) + 8 * (p >> 7);   // head linear = b*16+h; 8 heads/XCD
  const int qt = (p >> 3) & 15;
  const int b = hd >> 4, h = hd & 15;

  const int t = threadIdx.x, wave = t >> 6, lane = t & 63;
  const int r = lane & 15, g = lane >> 4;

  const __bf16* Qp = Q + (size_t)hd * (2048 * 64);
  const char* Kh = (const char*)(K + (size_t)hd * (2048 * 64));
  const char* Vh = (const char*)(Vt + (size_t)hd * (64 * 2048));
  const int q0 = qt * 128 + wave * 32;

  // Q fragments (pre-scaled by SCQ at QKV epilogue)
  bf16x8 qf[2][2];
  #pragma unroll
  for (int qh = 0; qh < 2; ++qh)
    #pragma unroll
    for (int hh = 0; hh < 2; ++hh)
      qf[qh][hh] =
          *(const bf16x8*)(Qp + (size_t)(q0 + qh * 16 + r) * 64 + hh * 32 + g * 8);

  float mrun[2] = {0.f, 0.f};
  float lrun[2] = {0.f, 0.f};   // lane-partial; reduced once in epilogue
  f32x4 o[4][2] = {};

  // staging: per thread 2 K + 2 V gload16; wave-uniform LDS dest
  const int lofs0 = wave * 1024;            // + rnd*4096
  const int gofs0 = wave * 1024 + lane * 16;

  #define STAGE(t32, bi)                                                  \
    {                                                                     \
      char* lb = lds[bi];                                                 \
      _Pragma("unroll")                                                   \
      for (int rnd = 0; rnd < 2; ++rnd) {                                 \
        const int fb = rnd * 4096 + gofs0;                                \
        gload16(Kh + (size_t)(t32) * 8192 + fb, lb + rnd * 4096 + lofs0); \
        gload16(Vh + (size_t)(fb >> 7) * 4096 + (size_t)(t32) * 128 +     \
                    (fb & 127),                                           \
                lb + 8192 + rnd * 4096 + lofs0);                          \
      }                                                                   \
    }

  STAGE(0, 0);
  __syncthreads();

  const int sw = (r & 7) << 4;   // byte XOR for swizzled reads

  for (int t32 = 0; t32 < 32; ++t32) {
    const int cur = t32 & 1;
    if (t32 < 31) STAGE(t32 + 1, cur ^ 1);   // async into other buffer

    const char* kb = lds[cur];
    const char* vb = lds[cur] + 8192;

    // --- QK^T (swapped): sacc[kt][qh] = S_log2[k=16kt+4g+rr][q=r] - m ---
    f32x4 sacc[4][2];
    const f32x4 seed0 = {-mrun[0], -mrun[0], -mrun[0], -mrun[0]};
    const f32x4 seed1 = {-mrun[1], -mrun[1], -mrun[1], -mrun[1]};
    __builtin_amdgcn_s_setprio(1);
    #pragma unroll
    for (int kt = 0; kt < 4; ++kt) {
      const int rowb = (kt * 16 + r) * 128;
      const bf16x8 kf0 = *(const bf16x8*)(kb + rowb + ((16 * g) ^ sw));
      const bf16x8 kf1 = *(const bf16x8*)(kb + rowb + ((64 + 16 * g) ^ sw));
      f32x4 s0 = MFMA16(kf0, qf[0][0], seed0);
      s0 = MFMA16(kf1, qf[0][1], s0);
      sacc[kt][0] = s0;
      f32x4 s1 = MFMA16(kf0, qf[1][0], seed1);
      s1 = MFMA16(kf1, qf[1][1], s1);
      sacc[kt][1] = s1;
    }
    __builtin_amdgcn_s_setprio(0);

    // --- softmax: defer-max, fused exp2+sum+cvt into pf ---
    bf16x8 pf[2][2];
    #pragma unroll
    for (int qh = 0; qh < 2; ++qh) {
      float a0 = fmaxf(fmaxf(sacc[0][qh][0], sacc[0][qh][1]),
                       fmaxf(sacc[0][qh][2], sacc[0][qh][3]));
      float a1 = fmaxf(fmaxf(sacc[1][qh][0], sacc[1][qh][1]),
                       fmaxf(sacc[1][qh][2], sacc[1][qh][3]));
      float a2 = fmaxf(fmaxf(sacc[2][qh][0], sacc[2][qh][1]),
                       fmaxf(sacc[2][qh][2], sacc[2][qh][3]));
      float a3 = fmaxf(fmaxf(sacc[3][qh][0], sacc[3][qh][1]),
                       fmaxf(sacc[3][qh][2], sacc[3][qh][3]));
      const float tm = fmaxf(fmaxf(a0, a1), fmaxf(a2, a3));  // lane-local

      float s = 0.f;
      if (__any(tm > 6.0f)) {        // rare path: true rescale
        float rm = fmaxf(tm, __shfl_xor(tm, 16));
        rm = fmaxf(rm, __shfl_xor(rm, 32));
        const float dl = fmaxf(rm, 0.f);
        const float al = exp2f(-dl);
        mrun[qh] += dl;
        #pragma unroll
        for (int kt = 0; kt < 4; ++kt)
          #pragma unroll
          for (int rr = 0; rr < 4; ++rr) {
            const float e = exp2f(sacc[kt][qh][rr] - dl);
            s += e;
            pf[qh][kt >> 1][(kt & 1) * 4 + rr] = (__bf16)e;
          }
        lrun[qh] = lrun[qh] * al + s;
        #pragma unroll
        for (int dt = 0; dt < 4; ++dt)
          #pragma unroll
          for (int rr = 0; rr < 4; ++rr)
            o[dt][qh][rr] *= al;
      } else {                        // common path: zero cross-lane ops
        #pragma unroll
        for (int kt = 0; kt < 4; ++kt)
          #pragma unroll
          for (int rr = 0; rr < 4; ++rr) {
            const float e = exp2f(sacc[kt][qh][rr]);
            s += e;
            pf[qh][kt >> 1][(kt & 1) * 4 + rr] = (__bf16)e;
          }
        lrun[qh] += s;
      }
    }

    // --- PV: A = V (sigma-ordered swizzled cols), B = P (same order) ---
    __builtin_amdgcn_s_setprio(1);
    #pragma unroll
    for (int c = 0; c < 2; ++c)
      #pragma unroll
      for (int dt = 0; dt < 4; ++dt) {
        const bf16x8 vf = *(const bf16x8*)(vb + (dt * 16 + r) * 128 +
                                           ((c * 64 + 16 * g) ^ sw));
        o[dt][0] = MFMA16(vf, pf[0][c], o[dt][0]);
        o[dt][1] = MFMA16(vf, pf[1][c], o[dt][1]);
      }
    __builtin_amdgcn_s_setprio(0);

    __syncthreads();   // drains staged loads; buf[cur] safe to overwrite
  }
  #undef STAGE

  // --- epilogue: reduce lrun across g-groups once, normalize, write ---
  #pragma unroll
  for (int qh = 0; qh < 2; ++qh) {
    float lr = lrun[qh];
    lr += __shfl_xor(lr, 16);
    lr += __shfl_xor(lr, 32);
    const float inv = 1.0f / lr;
    const int ss = q0 + qh * 16 + r;
    #pragma unroll
    for (int dt = 0; dt < 4; ++dt) {
      bf16x4 ov;
      #pragma unroll
      for (int rr = 0; rr < 4; ++rr)
        ov[rr] = (__bf16)(o[dt][qh][rr] * inv);
      *(bf16x4*)&AO[((size_t)b * 2048 + ss) * 1024 + h * 64 + dt * 16 + 4 * g] = ov;
    }
  }
}

// ---------------------------------------------------------------------------
extern "C" void kernel_launch(void* const* d_in, const int* in_sizes, int n_in,
                              void* d_out, int out_size, void* d_ws, size_t ws_size,
                              hipStream_t stream) {
  (void)in_sizes; (void)n_in; (void)out_size; (void)ws_size;
  const float* x      = (const float*)d_in[0];
  const float* w_qkv  = (const float*)d_in[1];
  const float* b_qkv  = (const float*)d_in[2];
  const float* w_proj = (const float*)d_in[3];
  const float* b_proj = (const float*)d_in[4];
  float* out = (float*)d_out;

  char* ws = (char*)d_ws;
  const size_t E2 = (size_t)8192 * 1024 * 2;  // bytes per [8192][1024] bf16
  __bf16* Qb  = (__bf16*)(ws);
  __bf16* Kb  = (__bf16*)(ws + E2);
  __bf16* Vt  = (__bf16*)(ws + 2 * E2);
  __bf16* Xb  = (__bf16*)(ws + 3 * E2);
  __bf16* AO  = Xb;  // Xb dead after qkv_gemm_b; reuse for attention output
  __bf16* Wqt = (__bf16*)(ws + 4 * E2);
  __bf16* Wpt = (__bf16*)(ws + 4 * E2 + (size_t)3072 * 1024 * 2);

  conv_x<<<4096, 256, 0, stream>>>(x, Xb);
  conv_wt<<<dim3(48, 16), 256, 0, stream>>>(w_qkv, Wqt, 1024, 3072);
  conv_wt<<<dim3(16, 16), 256, 0, stream>>>(w_proj, Wpt, 1024, 1024);
  qkv_gemm_b<<<1536, 256, 0, stream>>>(Xb, Wqt, b_qkv, Qb, Kb, Vt);
  attn_kernel<<<1024, 256, 0, stream>>>(Qb, Kb, Vt, AO);
  proj_gemm_b<<<512, 256, 0, stream>>>(AO, Wpt, b_proj, out);
}

// Round 11
// 241.284 us; speedup vs baseline: 1.5027x; 1.0178x over previous
//
#include <hip/hip_runtime.h>
#include <hip/hip_bf16.h>
#include <cstdint>

typedef __attribute__((ext_vector_type(8))) __bf16 bf16x8;
typedef __attribute__((ext_vector_type(4))) __bf16 bf16x4;
typedef __attribute__((ext_vector_type(4))) float f32x4;

#define MFMA16(a, b, c) __builtin_amdgcn_mfma_f32_16x16x32_bf16(a, b, c, 0, 0, 0)

static constexpr float SCQ = 0.18033688f;  // (1/sqrt(64)) * log2(e)

__device__ __forceinline__ void gload16(const void* g, void* l) {
  __builtin_amdgcn_global_load_lds(
      (const __attribute__((address_space(1))) void*)g,
      (__attribute__((address_space(3))) void*)l, 16, 0, 0);
}

// ---------------------------------------------------------------------------
// conv_x: f32 [8192][1024] -> bf16 same layout
// ---------------------------------------------------------------------------
__global__ __launch_bounds__(256) void conv_x(const float* __restrict__ in,
                                              __bf16* __restrict__ out) {
  const size_t i = ((size_t)blockIdx.x * 256 + threadIdx.x) * 8;
  const float4 v0 = *(const float4*)(in + i);
  const float4 v1 = *(const float4*)(in + i + 4);
  bf16x8 o = {(__bf16)v0.x, (__bf16)v0.y, (__bf16)v0.z, (__bf16)v0.w,
              (__bf16)v1.x, (__bf16)v1.y, (__bf16)v1.z, (__bf16)v1.w};
  *(bf16x8*)(out + i) = o;
}

// ---------------------------------------------------------------------------
// conv_wt: W f32 [K][N] -> Wt bf16 [N][K]  (transpose via LDS tile)
// ---------------------------------------------------------------------------
__global__ __launch_bounds__(256) void conv_wt(const float* __restrict__ W,
                                               __bf16* __restrict__ Wt,
                                               int K, int N) {
  __shared__ float tile[64][65];
  const int nb = blockIdx.x * 64, kb = blockIdx.y * 64;
  const int t = threadIdx.x, tr = t >> 4, tc = t & 15;
  #pragma unroll
  for (int p = 0; p < 4; ++p) {
    const float4 v =
        *(const float4*)(W + (size_t)(kb + p * 16 + tr) * N + nb + tc * 4);
    tile[p * 16 + tr][tc * 4 + 0] = v.x;
    tile[p * 16 + tr][tc * 4 + 1] = v.y;
    tile[p * 16 + tr][tc * 4 + 2] = v.z;
    tile[p * 16 + tr][tc * 4 + 3] = v.w;
  }
  __syncthreads();
  #pragma unroll
  for (int p = 0; p < 4; ++p) {
    const int n = p * 16 + tr, kk = tc * 4;
    bf16x4 o = {(__bf16)tile[kk + 0][n], (__bf16)tile[kk + 1][n],
                (__bf16)tile[kk + 2][n], (__bf16)tile[kk + 3][n]};
    *(bf16x4*)(Wt + (size_t)(nb + n) * K + kb + kk) = o;
  }
}

// ---------------------------------------------------------------------------
// GEMM, T4 counted-vmcnt schedule: BM=128, BN=256, BK=64, 8 waves (2Mx4N),
// per-wave 64x64 (acc[4][4]).  Triple-buffered LDS (3 x 48KB), staging 2
// tiles ahead via global_load_lds w=16 -> boundary wait is vmcnt(6), never
// a drain.  T2: LDS reads XOR-swizzled; realized by XOR-ing the per-lane
// GLOBAL source address (LDS stays linear; global layout unchanged).
// Raw s_barrier only (no __syncthreads -> no forced vmcnt(0)).
// MODE 0: qkv epilogue (scatter Q*SCQ, K xor-swizzled, V sigma+xor).
// MODE 1: proj epilogue (f32 + bias).
// ---------------------------------------------------------------------------
template <int MODE>
__global__ __launch_bounds__(512) void gemm_t4(
    const __bf16* __restrict__ A, const __bf16* __restrict__ Bt,
    const float* __restrict__ bias,
    __bf16* __restrict__ Qb, __bf16* __restrict__ Kb, __bf16* __restrict__ Vt,
    float* __restrict__ outF)
{
  __shared__ alignas(16) char lds_[3 * 49152];   // [buf][A 16KB | B 32KB]

  const int id = blockIdx.x;
  constexpr int NB = (MODE == 0) ? 12 : 4;       // N-blocks per M-row
  constexpr int CH = (MODE == 0) ? 96 : 32;      // blocks per XCD (bijective)
  const int wg = (id & 7) * CH + (id >> 3);
  const int m0 = (wg / NB) * 128;
  const int n0 = (wg % NB) * 256;

  const int t = threadIdx.x, w = t >> 6, lane = t & 63;
  const int r = lane & 15, g = lane >> 4;
  const int wr = w >> 2, wc = w & 3;             // wave: M-half, N-quarter

  const char* Ac = (const char*)A + (size_t)m0 * 2048;
  const char* Bc = (const char*)Bt + (size_t)n0 * 2048;

  // staging: A tile 128x64 (16KB, 2 rounds), B tile 256x64 (32KB, 4 rounds);
  // source col-chunk XOR (row&7) so linear LDS holds swizzled data.
  #define STAGE(kt_)                                                       \
    {                                                                      \
      char* lb = lds_ + ((kt_) % 3) * 49152;                               \
      _Pragma("unroll")                                                    \
      for (int rnd = 0; rnd < 2; ++rnd) {                                  \
        const int c = rnd * 512 + t;                                       \
        const int row = c >> 3;                                            \
        const int kc = (c & 7) ^ (row & 7);                                \
        gload16(Ac + (size_t)row * 2048 + (kt_) * 128 + kc * 16,           \
                lb + rnd * 8192 + t * 16);                                 \
      }                                                                    \
      _Pragma("unroll")                                                    \
      for (int rnd = 0; rnd < 4; ++rnd) {                                  \
        const int c = rnd * 512 + t;                                       \
        const int row = c >> 3;                                            \
        const int kc = (c & 7) ^ (row & 7);                                \
        gload16(Bc + (size_t)row * 2048 + (kt_) * 128 + kc * 16,           \
                lb + 16384 + rnd * 8192 + t * 16);                         \
      }                                                                    \
    }

  f32x4 acc[4][4] = {};
  const int sw = (r & 7) << 4;

  // prologue: tiles 0,1 in flight; retire tile 0 (vmcnt(6) leaves tile 1's 6)
  STAGE(0);
  STAGE(1);
  asm volatile("s_waitcnt vmcnt(6)" ::: "memory");
  __builtin_amdgcn_sched_barrier(0);
  __builtin_amdgcn_s_barrier();
  __builtin_amdgcn_sched_barrier(0);

  for (int kt = 0; kt < 16; ++kt) {
    if (kt < 14) STAGE(kt + 2);
    const char* lb = lds_ + (kt % 3) * 49152;

    // ---- phase 0: j = 0,1 ----
    bf16x8 af[4][2], bf0[2][2];
    #pragma unroll
    for (int i = 0; i < 4; ++i)
      #pragma unroll
      for (int kk = 0; kk < 2; ++kk)
        af[i][kk] = *(const bf16x8*)(lb + (wr * 64 + i * 16 + r) * 128 +
                                     ((kk * 64 + g * 16) ^ sw));
    #pragma unroll
    for (int jj = 0; jj < 2; ++jj)
      #pragma unroll
      for (int kk = 0; kk < 2; ++kk)
        bf0[jj][kk] = *(const bf16x8*)(lb + 16384 +
                                       (wc * 64 + jj * 16 + r) * 128 +
                                       ((kk * 64 + g * 16) ^ sw));
    asm volatile("s_waitcnt lgkmcnt(0)" ::: "memory");
    __builtin_amdgcn_sched_barrier(0);
    __builtin_amdgcn_s_setprio(1);
    #pragma unroll
    for (int kk = 0; kk < 2; ++kk)
      #pragma unroll
      for (int i = 0; i < 4; ++i)
        #pragma unroll
        for (int jj = 0; jj < 2; ++jj)
          acc[i][jj] = MFMA16(af[i][kk], bf0[jj][kk], acc[i][jj]);
    __builtin_amdgcn_s_setprio(0);
    __builtin_amdgcn_s_barrier();
    __builtin_amdgcn_sched_barrier(0);

    // ---- phase 1: j = 2,3 ----
    bf16x8 bf1[2][2];
    #pragma unroll
    for (int jj = 0; jj < 2; ++jj)
      #pragma unroll
      for (int kk = 0; kk < 2; ++kk)
        bf1[jj][kk] = *(const bf16x8*)(lb + 16384 +
                                       (wc * 64 + (2 + jj) * 16 + r) * 128 +
                                       ((kk * 64 + g * 16) ^ sw));
    asm volatile("s_waitcnt lgkmcnt(0)" ::: "memory");
    __builtin_amdgcn_sched_barrier(0);
    __builtin_amdgcn_s_setprio(1);
    #pragma unroll
    for (int kk = 0; kk < 2; ++kk)
      #pragma unroll
      for (int i = 0; i < 4; ++i)
        #pragma unroll
        for (int jj = 0; jj < 2; ++jj)
          acc[i][2 + jj] = MFMA16(af[i][kk], bf1[jj][kk], acc[i][2 + jj]);
    __builtin_amdgcn_s_setprio(0);

    // ---- tile boundary: counted wait (next tile retired, tile+2 in flight)
    if (kt < 14) {
      asm volatile("s_waitcnt vmcnt(6)" ::: "memory");
    } else {
      asm volatile("s_waitcnt vmcnt(0)" ::: "memory");
    }
    __builtin_amdgcn_sched_barrier(0);
    __builtin_amdgcn_s_barrier();
    __builtin_amdgcn_sched_barrier(0);
  }
  #undef STAGE

  // ---- epilogue ----
  if (MODE == 0) {
    const int which = n0 >> 10;  // 0=Q 1=K 2=V (256-tile never straddles)
    const int bb = m0 >> 11;
    const int sbase = (m0 & 2047) + wr * 64;
    #pragma unroll
    for (int j = 0; j < 4; ++j) {
      const int nc = n0 + wc * 64 + j * 16 + r;
      const float bv = bias[nc];
      const int hh = (nc & 1023) >> 6;
      const int d = nc & 63;
      #pragma unroll
      for (int i = 0; i < 4; ++i) {
        const int ss0 = sbase + i * 16 + g * 4;
        if (which == 0) {
          #pragma unroll
          for (int rr = 0; rr < 4; ++rr)
            Qb[((size_t)(bb * 16 + hh) * 2048 + ss0 + rr) * 64 + d] =
                (__bf16)((acc[i][j][rr] + bv) * SCQ);
        } else if (which == 1) {
          #pragma unroll
          for (int rr = 0; rr < 4; ++rr)
            Kb[((size_t)(bb * 16 + hh) * 2048 + ss0 + rr) * 64 +
               (d ^ ((((ss0 + rr) & 7)) << 3))] =
                (__bf16)(acc[i][j][rr] + bv);
        } else {
          bf16x4 vv;
          #pragma unroll
          for (int rr = 0; rr < 4; ++rr) vv[rr] = (__bf16)(acc[i][j][rr] + bv);
          const int v5 = ss0 & 31;  // multiple of 4
          const int pcol = (ss0 & ~31) + 8 * ((v5 >> 2) & 3) + 4 * (v5 >> 4);
          const int scol2 = (pcol & ~127) | ((pcol & 127) ^ ((d & 7) << 3));
          *(bf16x4*)&Vt[((size_t)(bb * 16 + hh) * 64 + d) * 2048 + scol2] = vv;
        }
      }
    }
  } else {
    #pragma unroll
    for (int j = 0; j < 4; ++j) {
      const int nc = n0 + wc * 64 + j * 16 + r;
      const float bv = bias[nc];
      #pragma unroll
      for (int i = 0; i < 4; ++i)
        #pragma unroll
        for (int rr = 0; rr < 4; ++rr)
          outF[(size_t)(m0 + wr * 64 + i * 16 + g * 4 + rr) * 1024 + nc] =
              acc[i][j][rr] + bv;
    }
  }
}

// ---------------------------------------------------------------------------
// Flash attention (unchanged from round 10): gload_lds staging of XOR-
// swizzled K/V, double-buffered, one __syncthreads per tile; swapped QK^T,
// seeded-C, defer-max, lane-local sigma-ordered P.
// ---------------------------------------------------------------------------
__global__ __launch_bounds__(256, 4) void attn_kernel(
    const __bf16* __restrict__ Q, const __bf16* __restrict__ K,
    const __bf16* __restrict__ Vt, __bf16* __restrict__ AO)
{
  __shared__ alignas(16) char lds[2][16384];   // [buf][ K 8KB | V 8KB ]

  const int p = blockIdx.x;
  const int hd = (p & 7) + 8 * (p >> 7);   // head linear = b*16+h; 8 heads/XCD
  const int qt = (p >> 3) & 15;
  const int b = hd >> 4, h = hd & 15;

  const int t = threadIdx.x, wave = t >> 6, lane = t & 63;
  const int r = lane & 15, g = lane >> 4;

  const __bf16* Qp = Q + (size_t)hd * (2048 * 64);
  const char* Kh = (const char*)(K + (size_t)hd * (2048 * 64));
  const char* Vh = (const char*)(Vt + (size_t)hd * (64 * 2048));
  const int q0 = qt * 128 + wave * 32;

  bf16x8 qf[2][2];
  #pragma unroll
  for (int qh = 0; qh < 2; ++qh)
    #pragma unroll
    for (int hh = 0; hh < 2; ++hh)
      qf[qh][hh] =
          *(const bf16x8*)(Qp + (size_t)(q0 + qh * 16 + r) * 64 + hh * 32 + g * 8);

  float mrun[2] = {0.f, 0.f};
  float lrun[2] = {0.f, 0.f};
  f32x4 o[4][2] = {};

  const int lofs0 = wave * 1024;
  const int gofs0 = wave * 1024 + lane * 16;

  #define STAGE(t32, bi)                                                  \
    {                                                                     \
      char* lb = lds[bi];                                                 \
      _Pragma("unroll")                                                   \
      for (int rnd = 0; rnd < 2; ++rnd) {                                 \
        const int fb = rnd * 4096 + gofs0;                                \
        gload16(Kh + (size_t)(t32) * 8192 + fb, lb + rnd * 4096 + lofs0); \
        gload16(Vh + (size_t)(fb >> 7) * 4096 + (size_t)(t32) * 128 +     \
                    (fb & 127),                                           \
                lb + 8192 + rnd * 4096 + lofs0);                          \
      }                                                                   \
    }

  STAGE(0, 0);
  __syncthreads();

  const int sw = (r & 7) << 4;

  for (int t32 = 0; t32 < 32; ++t32) {
    const int cur = t32 & 1;
    if (t32 < 31) STAGE(t32 + 1, cur ^ 1);

    const char* kb = lds[cur];
    const char* vb = lds[cur] + 8192;

    f32x4 sacc[4][2];
    const f32x4 seed0 = {-mrun[0], -mrun[0], -mrun[0], -mrun[0]};
    const f32x4 seed1 = {-mrun[1], -mrun[1], -mrun[1], -mrun[1]};
    __builtin_amdgcn_s_setprio(1);
    #pragma unroll
    for (int kt = 0; kt < 4; ++kt) {
      const int rowb = (kt * 16 + r) * 128;
      const bf16x8 kf0 = *(const bf16x8*)(kb + rowb + ((16 * g) ^ sw));
      const bf16x8 kf1 = *(const bf16x8*)(kb + rowb + ((64 + 16 * g) ^ sw));
      f32x4 s0 = MFMA16(kf0, qf[0][0], seed0);
      s0 = MFMA16(kf1, qf[0][1], s0);
      sacc[kt][0] = s0;
      f32x4 s1 = MFMA16(kf0, qf[1][0], seed1);
      s1 = MFMA16(kf1, qf[1][1], s1);
      sacc[kt][1] = s1;
    }
    __builtin_amdgcn_s_setprio(0);

    bf16x8 pf[2][2];
    #pragma unroll
    for (int qh = 0; qh < 2; ++qh) {
      float a0 = fmaxf(fmaxf(sacc[0][qh][0], sacc[0][qh][1]),
                       fmaxf(sacc[0][qh][2], sacc[0][qh][3]));
      float a1 = fmaxf(fmaxf(sacc[1][qh][0], sacc[1][qh][1]),
                       fmaxf(sacc[1][qh][2], sacc[1][qh][3]));
      float a2 = fmaxf(fmaxf(sacc[2][qh][0], sacc[2][qh][1]),
                       fmaxf(sacc[2][qh][2], sacc[2][qh][3]));
      float a3 = fmaxf(fmaxf(sacc[3][qh][0], sacc[3][qh][1]),
                       fmaxf(sacc[3][qh][2], sacc[3][qh][3]));
      const float tm = fmaxf(fmaxf(a0, a1), fmaxf(a2, a3));

      float s = 0.f;
      if (__any(tm > 6.0f)) {
        float rm = fmaxf(tm, __shfl_xor(tm, 16));
        rm = fmaxf(rm, __shfl_xor(rm, 32));
        const float dl = fmaxf(rm, 0.f);
        const float al = exp2f(-dl);
        mrun[qh] += dl;
        #pragma unroll
        for (int kt = 0; kt < 4; ++kt)
          #pragma unroll
          for (int rr = 0; rr < 4; ++rr) {
            const float e = exp2f(sacc[kt][qh][rr] - dl);
            s += e;
            pf[qh][kt >> 1][(kt & 1) * 4 + rr] = (__bf16)e;
          }
        lrun[qh] = lrun[qh] * al + s;
        #pragma unroll
        for (int dt = 0; dt < 4; ++dt)
          #pragma unroll
          for (int rr = 0; rr < 4; ++rr)
            o[dt][qh][rr] *= al;
      } else {
        #pragma unroll
        for (int kt = 0; kt < 4; ++kt)
          #pragma unroll
          for (int rr = 0; rr < 4; ++rr) {
            const float e = exp2f(sacc[kt][qh][rr]);
            s += e;
            pf[qh][kt >> 1][(kt & 1) * 4 + rr] = (__bf16)e;
          }
        lrun[qh] += s;
      }
    }

    __builtin_amdgcn_s_setprio(1);
    #pragma unroll
    for (int c = 0; c < 2; ++c)
      #pragma unroll
      for (int dt = 0; dt < 4; ++dt) {
        const bf16x8 vf = *(const bf16x8*)(vb + (dt * 16 + r) * 128 +
                                           ((c * 64 + 16 * g) ^ sw));
        o[dt][0] = MFMA16(vf, pf[0][c], o[dt][0]);
        o[dt][1] = MFMA16(vf, pf[1][c], o[dt][1]);
      }
    __builtin_amdgcn_s_setprio(0);

    __syncthreads();
  }
  #undef STAGE

  #pragma unroll
  for (int qh = 0; qh < 2; ++qh) {
    float lr = lrun[qh];
    lr += __shfl_xor(lr, 16);
    lr += __shfl_xor(lr, 32);
    const float inv = 1.0f / lr;
    const int ss = q0 + qh * 16 + r;
    #pragma unroll
    for (int dt = 0; dt < 4; ++dt) {
      bf16x4 ov;
      #pragma unroll
      for (int rr = 0; rr < 4; ++rr)
        ov[rr] = (__bf16)(o[dt][qh][rr] * inv);
      *(bf16x4*)&AO[((size_t)b * 2048 + ss) * 1024 + h * 64 + dt * 16 + 4 * g] = ov;
    }
  }
}

// ---------------------------------------------------------------------------
extern "C" void kernel_launch(void* const* d_in, const int* in_sizes, int n_in,
                              void* d_out, int out_size, void* d_ws, size_t ws_size,
                              hipStream_t stream) {
  (void)in_sizes; (void)n_in; (void)out_size; (void)ws_size;
  const float* x      = (const float*)d_in[0];
  const float* w_qkv  = (const float*)d_in[1];
  const float* b_qkv  = (const float*)d_in[2];
  const float* w_proj = (const float*)d_in[3];
  const float* b_proj = (const float*)d_in[4];
  float* out = (float*)d_out;

  char* ws = (char*)d_ws;
  const size_t E2 = (size_t)8192 * 1024 * 2;  // bytes per [8192][1024] bf16
  __bf16* Qb  = (__bf16*)(ws);
  __bf16* Kb  = (__bf16*)(ws + E2);
  __bf16* Vt  = (__bf16*)(ws + 2 * E2);
  __bf16* Xb  = (__bf16*)(ws + 3 * E2);
  __bf16* AO  = Xb;  // Xb dead after qkv GEMM; reuse for attention output
  __bf16* Wqt = (__bf16*)(ws + 4 * E2);
  __bf16* Wpt = (__bf16*)(ws + 4 * E2 + (size_t)3072 * 1024 * 2);

  conv_x<<<4096, 256, 0, stream>>>(x, Xb);
  conv_wt<<<dim3(48, 16), 256, 0, stream>>>(w_qkv, Wqt, 1024, 3072);
  conv_wt<<<dim3(16, 16), 256, 0, stream>>>(w_proj, Wpt, 1024, 1024);
  gemm_t4<0><<<768, 512, 0, stream>>>(Xb, Wqt, b_qkv, Qb, Kb, Vt, nullptr);
  attn_kernel<<<1024, 256, 0, stream>>>(Qb, Kb, Vt, AO);
  gemm_t4<1><<<256, 512, 0, stream>>>(AO, Wpt, b_proj, nullptr, nullptr,
                                      nullptr, out);
}